// Round 7
// baseline (851.280 us; speedup 1.0000x reference)
//
#include <hip/hip_runtime.h>
#include <hip/hip_bf16.h>

// Problem constants (fixed by the reference file).
constexpr int N_NODES = 20000;
constexpr int N_EDGES = 640000;
constexpr int D = 128;          // D_IN == D_OUT == 128
constexpr int N_TILES_NODE = (N_NODES + 63) / 64;   // 313
constexpr int SCAT_BLOCKS  = (N_EDGES + 255) / 256; // 2500 (fallback scatter)
constexpr int CONV_BLOCKS  = N_EDGES / 128;         // 5000 (scatter-convert)
constexpr int EDGE_BLOCKS  = N_NODES / 4;           // 5000: 1 node per wave

typedef float  f32x4  __attribute__((ext_vector_type(4)));
typedef short  short8 __attribute__((ext_vector_type(8)));

// fp32 -> bf16 bits, round-to-nearest-even (scalar)
__device__ inline short f2bf(float f) {
    unsigned u = __builtin_bit_cast(unsigned, f);
    u += 0x7fffu + ((u >> 16) & 1u);
    return (short)(u >> 16);
}
__device__ inline float bf2f(short s) {
    unsigned u = ((unsigned)(unsigned short)s) << 16;
    return __builtin_bit_cast(float, u);
}
// packed fp32x2 -> bf16x2 (RNE), single HW instruction
__device__ inline unsigned cvt_pk_bf16(float a, float b) {
    unsigned r;
    asm("v_cvt_pk_bf16_f32 %0, %1, %2" : "=v"(r) : "v"(a), "v"(b));
    return r;
}

// ---------------------------------------------------------------------------
// Prep: weight fragments (We -> fragE bf16; Wn -> fragH/fragL hi/lo split)
// + zero the counting-sort histogram.
// ---------------------------------------------------------------------------
__global__ __launch_bounds__(256) void prep_kernel(
    const float* __restrict__ We, const float* __restrict__ Wn,
    short8* __restrict__ fragE, short8* __restrict__ fragH,
    short8* __restrict__ fragL, int* __restrict__ count)
{
    const int t = blockIdx.x * 256 + threadIdx.x;   // 2048 threads
    for (int i = t; i < N_NODES; i += 2048) count[i] = 0;

    const int n = t >> 4, k8 = t & 15;
    const int kt = k8 >> 2, q = k8 & 3;
    const int fi = ((n >> 4) * 4 + kt) * 64 + q * 16 + (n & 15);

    {
        const float4 x = *(const float4*)(We + n * D + k8 * 8);
        const float4 y = *(const float4*)(We + n * D + k8 * 8 + 4);
        short8 s;
        unsigned* sp = (unsigned*)&s;
        sp[0] = cvt_pk_bf16(x.x, x.y);
        sp[1] = cvt_pk_bf16(x.z, x.w);
        sp[2] = cvt_pk_bf16(y.x, y.y);
        sp[3] = cvt_pk_bf16(y.z, y.w);
        fragE[fi] = s;
    }
    {
        const float4 x = *(const float4*)(Wn + n * D + k8 * 8);
        const float4 y = *(const float4*)(Wn + n * D + k8 * 8 + 4);
        const float v[8] = {x.x, x.y, x.z, x.w, y.x, y.y, y.z, y.w};
        short8 hi, lo;
        #pragma unroll
        for (int j = 0; j < 8; ++j) {
            hi[j] = f2bf(v[j]);
            lo[j] = f2bf(v[j] - bf2f(hi[j]));
        }
        fragH[fi] = hi;
        fragL[fi] = lo;
    }
}

// ---------------------------------------------------------------------------
// Counting sort: histogram, scan (keeps a durable copy of the offsets).
// ---------------------------------------------------------------------------
__global__ __launch_bounds__(256) void hist_kernel(
    const int* __restrict__ dst, int* __restrict__ count)
{
    const int e = blockIdx.x * 256 + threadIdx.x;
    if (e < N_EDGES) atomicAdd(&count[dst[e]], 1);
}

__global__ __launch_bounds__(1024) void scan_kernel(
    const int* __restrict__ count, int* __restrict__ cursor,
    int* __restrict__ off)
{
    constexpr int PER = 20;                    // 1024*20 = 20480 >= 20000
    __shared__ int tot[1024];
    const int tid = threadIdx.x;
    const int base = tid * PER;

    int local[PER];
    int s = 0;
    #pragma unroll
    for (int i = 0; i < PER; ++i) {
        const int idx = base + i;
        const int v = (idx < N_NODES) ? count[idx] : 0;
        local[i] = s;
        s += v;
    }
    tot[tid] = s;
    __syncthreads();
    for (int offp = 1; offp < 1024; offp <<= 1) {
        const int add = (tid >= offp) ? tot[tid - offp] : 0;
        __syncthreads();
        tot[tid] += add;
        __syncthreads();
    }
    const int excl = tot[tid] - s;
    #pragma unroll
    for (int i = 0; i < PER; ++i) {
        const int idx = base + i;
        if (idx < N_NODES) {
            const int v = excl + local[i];
            cursor[idx] = v;     // consumed (and destroyed) by scatter
            off[idx]    = v;     // durable per-node run offsets for edge pass
        }
    }
    if (tid == 0) off[N_NODES] = N_EDGES;
}

// ---------------------------------------------------------------------------
// Node tile body: h = nf @ Wn.T + bn (hi/lo bf16 split, ~fp32 exact),
// h -> workspace; out = relu(h + res_w) / degs (residual init).
// ---------------------------------------------------------------------------
__device__ __forceinline__ void node_tile(
    int tb, int tid,
    const float* __restrict__ nf, const float* __restrict__ degs,
    const short8* __restrict__ fragH, const short8* __restrict__ fragL,
    const float* __restrict__ bn, const float* __restrict__ res_w,
    float* __restrict__ h_ws, float* __restrict__ out)
{
    const int lane = tid & 63, wave = tid >> 6;
    const int quad = lane >> 4, row16 = lane & 15;
    const int mbase = tb * 64 + wave * 16;

    const int arow = min(mbase + row16, N_NODES - 1);
    short8 ah[4], al[4];
    const float* p = nf + arow * D + quad * 8;
    #pragma unroll
    for (int kt = 0; kt < 4; ++kt) {
        const float4 x = *(const float4*)(p + kt * 32);
        const float4 y = *(const float4*)(p + kt * 32 + 4);
        const float v[8] = {x.x, x.y, x.z, x.w, y.x, y.y, y.z, y.w};
        #pragma unroll
        for (int j = 0; j < 8; ++j) {
            ah[kt][j] = f2bf(v[j]);
            al[kt][j] = f2bf(v[j] - bf2f(ah[kt][j]));
        }
    }

    int   orow[4];
    float dinv[4];
    #pragma unroll
    for (int r = 0; r < 4; ++r) {
        orow[r] = mbase + quad * 4 + r;
        dinv[r] = 1.0f / degs[min(orow[r], N_NODES - 1)];
    }

    #pragma unroll
    for (int nt = 0; nt < 8; ++nt) {
        f32x4 acc = {0.f, 0.f, 0.f, 0.f};
        #pragma unroll
        for (int kt = 0; kt < 4; ++kt) {
            const short8 bh = fragH[(nt * 4 + kt) * 64 + lane];
            const short8 bl = fragL[(nt * 4 + kt) * 64 + lane];
            acc = __builtin_amdgcn_mfma_f32_16x16x32_bf16(al[kt], bh, acc, 0, 0, 0);
            acc = __builtin_amdgcn_mfma_f32_16x16x32_bf16(ah[kt], bl, acc, 0, 0, 0);
            acc = __builtin_amdgcn_mfma_f32_16x16x32_bf16(ah[kt], bh, acc, 0, 0, 0);
        }
        const int col = nt * 16 + row16;
        const float bnv = bn[col], rwv = res_w[col];
        #pragma unroll
        for (int r = 0; r < 4; ++r) {
            if (orow[r] < N_NODES) {
                const float hv = acc[r] + bnv;
                h_ws[orow[r] * D + col] = hv;
                out[orow[r] * D + col] = fmaxf(hv + rwv, 0.0f) * dinv[r];
            }
        }
    }
}

// ---------------------------------------------------------------------------
// NEW mid kernel: node tiles (blocks [0,313)) + SCATTER-CONVERT (rest).
// Scatter-convert: read ef rows in NATURAL order (perfectly streamed),
// convert to bf16, and scatter-write the 256B row to its dst-sorted position
// efs[pos] (pos from the cursor atomic).  The random side is now fire-and-
// forget WRITES into a 164 MB buffer that fits the 256 MB LLC -> no DRAM
// row-activation bottleneck.  Also writes snp[pos] = {src, norm_bits}.
// Layout: 16 lanes per edge row; lane16 covers cols [lane16*8, +8).
// ---------------------------------------------------------------------------
__global__ __launch_bounds__(256) void mid_kernel(
    const int* __restrict__ dst, int* __restrict__ cursor,
    const int* __restrict__ src, const float* __restrict__ norm,
    const float* __restrict__ ef, short8* __restrict__ efs,
    int2* __restrict__ snp,
    const float* __restrict__ nf, const float* __restrict__ degs,
    const short8* __restrict__ fragH, const short8* __restrict__ fragL,
    const float* __restrict__ bn, const float* __restrict__ res_w,
    float* __restrict__ h_ws, float* __restrict__ out)
{
    if (blockIdx.x < N_TILES_NODE) {
        node_tile(blockIdx.x, threadIdx.x, nf, degs, fragH, fragL,
                  bn, res_w, h_ws, out);
        return;
    }
    const int blk   = blockIdx.x - N_TILES_NODE;   // 0..CONV_BLOCKS-1
    const int tid   = threadIdx.x;
    const int lane  = tid & 63;
    const int l16   = lane & 15;            // lane within 16-lane row group
    const int grp   = tid >> 4;             // 16 row groups per block

    #pragma unroll
    for (int it = 0; it < 8; ++it) {
        const int e = blk * 128 + it * 16 + grp;      // natural edge order

        int pos = 0;
        if (l16 == 0) pos = atomicAdd(&cursor[dst[e]], 1);
        pos = __shfl(pos, lane & 48, 64);             // group leader broadcast

        // streamed read: group's 16 lanes cover the 512B row contiguously
        const float4 x = *(const float4*)(ef + e * D + l16 * 8);
        const float4 y = *(const float4*)(ef + e * D + l16 * 8 + 4);
        short8 s;
        unsigned* sp = (unsigned*)&s;
        sp[0] = cvt_pk_bf16(x.x, x.y);
        sp[1] = cvt_pk_bf16(x.z, x.w);
        sp[2] = cvt_pk_bf16(y.x, y.y);
        sp[3] = cvt_pk_bf16(y.z, y.w);
        efs[pos * 16 + l16] = s;                      // scattered 256B row

        if (l16 == 0) snp[pos] = make_int2(src[e], __float_as_int(norm[e]));
    }
}

// ---------------------------------------------------------------------------
// NEW edge kernel: ONE WAVE PER DESTINATION NODE, fully STREAMING reads.
// The wave processes its node's contiguous run [off[n], off[n+1]) of the
// pre-gathered bf16 rows efs:  e = efs @ We.T (MFMA)  ->
// msg = norm*relu(h[src]+e+be) -> in-register column sums -> one exclusive
// RMW out[n][col] += colsum.  No atomics, no LDS, no barriers, no gathers
// from DRAM (efs/snp stream; h hits LLC).
// ---------------------------------------------------------------------------
__global__ __launch_bounds__(256) void edge_kernel(
    const short8* __restrict__ efs, const int2* __restrict__ snp,
    const int* __restrict__ off,
    const short8* __restrict__ fragE, const float* __restrict__ be,
    const float* __restrict__ h, float* __restrict__ out)
{
    const int t = threadIdx.x;
    const int lane  = t & 63;
    const int quad  = lane >> 4;
    const int row16 = lane & 15;
    const int wave  = t >> 6;
    const int node  = blockIdx.x * 4 + wave;     // EDGE_BLOCKS*4 == N_NODES

    const int off0 = off[node];
    const int deg  = off[node + 1] - off0;
    if (deg == 0) return;

    float colsum[8] = {0.f, 0.f, 0.f, 0.f, 0.f, 0.f, 0.f, 0.f};

    for (int c0 = 0; c0 < deg; c0 += 32) {
        // ---- A fragments: direct bf16 loads from the streamed-sorted rows
        short8 afr[2][4];
        #pragma unroll
        for (int mt = 0; mt < 2; ++mt) {
            const int p = off0 + min(c0 + mt * 16 + row16, deg - 1);
            #pragma unroll
            for (int kt = 0; kt < 4; ++kt)
                afr[mt][kt] = efs[p * 16 + kt * 4 + quad];
        }

        // ---- Metadata for the epilogue rows this lane owns (m = quad*4+r);
        //      pad rows (pos >= deg) get nrm = 0 -> contribute 0.
        int   sidx[2][4];
        float nrm[2][4];
        #pragma unroll
        for (int mt = 0; mt < 2; ++mt) {
            #pragma unroll
            for (int r = 0; r < 4; ++r) {
                const int pos = c0 + mt * 16 + quad * 4 + r;
                const int2 v = snp[off0 + min(pos, deg - 1)];
                sidx[mt][r] = v.x;
                nrm[mt][r]  = (pos < deg) ? __int_as_float(v.y) : 0.0f;
            }
        }

        #pragma unroll
        for (int g = 0; g < 4; ++g) {
            // h gathers for this group's two 16-col tiles (LLC-resident)
            float hv[2][2][4];
            #pragma unroll
            for (int t2 = 0; t2 < 2; ++t2)
                #pragma unroll
                for (int mt = 0; mt < 2; ++mt)
                    #pragma unroll
                    for (int r = 0; r < 4; ++r)
                        hv[t2][mt][r] =
                            h[sidx[mt][r] * D + (g * 2 + t2) * 16 + row16];

            // MFMA both column tiles
            f32x4 acc[2][2];
            #pragma unroll
            for (int t2 = 0; t2 < 2; ++t2) {
                const int nt = g * 2 + t2;
                short8 bfr[4];
                #pragma unroll
                for (int kt = 0; kt < 4; ++kt)
                    bfr[kt] = fragE[(nt * 4 + kt) * 64 + lane];
                f32x4 a0 = {0.f, 0.f, 0.f, 0.f};
                f32x4 a1 = {0.f, 0.f, 0.f, 0.f};
                #pragma unroll
                for (int kt = 0; kt < 4; ++kt) {
                    a0 = __builtin_amdgcn_mfma_f32_16x16x32_bf16(afr[0][kt], bfr[kt], a0, 0, 0, 0);
                    a1 = __builtin_amdgcn_mfma_f32_16x16x32_bf16(afr[1][kt], bfr[kt], a1, 0, 0, 0);
                }
                acc[t2][0] = a0;
                acc[t2][1] = a1;
            }

            // epilogue: msg = norm*relu(h + e + be), summed over this lane's
            // 8 m-positions straight into the per-col accumulator
            #pragma unroll
            for (int t2 = 0; t2 < 2; ++t2) {
                const int nt = g * 2 + t2;
                const float bev = be[nt * 16 + row16];
                float s = 0.0f;
                #pragma unroll
                for (int r = 0; r < 4; ++r) {
                    s += nrm[0][r] * fmaxf(hv[t2][0][r] + acc[t2][0][r] + bev, 0.0f);
                    s += nrm[1][r] * fmaxf(hv[t2][1][r] + acc[t2][1][r] + bev, 0.0f);
                }
                colsum[nt] += s;
            }
        }
    }

    // ---- cross-quad reduction: lane bits 4,5 are the quad -> two butterflies
    #pragma unroll
    for (int nt = 0; nt < 8; ++nt) {
        float v = colsum[nt];
        v += __shfl_xor(v, 16, 64);
        v += __shfl_xor(v, 32, 64);
        colsum[nt] = v;
    }

    // ---- single exclusive-owner RMW: quad q writes nt = 2q, 2q+1
    const int base = node * D;
    #pragma unroll
    for (int j = 0; j < 2; ++j) {
        const int nt  = quad * 2 + j;
        const int col = nt * 16 + row16;
        out[base + col] += colsum[nt];
    }
}

// ---------------------------------------------------------------------------
// FALLBACK path (R6 structure: perm-scatter + f32 ef gather) -- used only if
// the workspace cannot hold the 164 MB efs buffer.
// ---------------------------------------------------------------------------
__global__ __launch_bounds__(256) void mid_fb(
    const int* __restrict__ dst, int* __restrict__ cursor,
    int* __restrict__ perm,
    const float* __restrict__ nf, const float* __restrict__ degs,
    const short8* __restrict__ fragH, const short8* __restrict__ fragL,
    const float* __restrict__ bn, const float* __restrict__ res_w,
    float* __restrict__ h_ws, float* __restrict__ out)
{
    if (blockIdx.x < N_TILES_NODE) {
        node_tile(blockIdx.x, threadIdx.x, nf, degs, fragH, fragL,
                  bn, res_w, h_ws, out);
    } else {
        const int e = (blockIdx.x - N_TILES_NODE) * 256 + threadIdx.x;
        if (e < N_EDGES) {
            const int pos = atomicAdd(&cursor[dst[e]], 1);
            perm[pos] = e;
        }
    }
}

__global__ __launch_bounds__(256) void edge_fb(
    const float* __restrict__ ef, const float* __restrict__ norm,
    const int* __restrict__ src, const int* __restrict__ perm,
    const int* __restrict__ off,
    const short8* __restrict__ fragE, const float* __restrict__ be,
    const float* __restrict__ h, float* __restrict__ out)
{
    const int t = threadIdx.x;
    const int lane  = t & 63;
    const int quad  = lane >> 4;
    const int row16 = lane & 15;
    const int wave  = t >> 6;
    const int node  = blockIdx.x * 4 + wave;

    const int off0 = off[node];
    const int deg  = off[node + 1] - off0;
    if (deg == 0) return;

    float colsum[8] = {0.f, 0.f, 0.f, 0.f, 0.f, 0.f, 0.f, 0.f};

    for (int c0 = 0; c0 < deg; c0 += 32) {
        short8 afr[2][4];
        #pragma unroll
        for (int mt = 0; mt < 2; ++mt) {
            const int erow = perm[off0 + min(c0 + mt * 16 + row16, deg - 1)];
            const float* p = ef + erow * D + quad * 8;
            #pragma unroll
            for (int kt = 0; kt < 4; ++kt) {
                const float4 x = *(const float4*)(p + kt * 32);
                const float4 y = *(const float4*)(p + kt * 32 + 4);
                short8 a;
                unsigned* ap = (unsigned*)&a;
                ap[0] = cvt_pk_bf16(x.x, x.y);
                ap[1] = cvt_pk_bf16(x.z, x.w);
                ap[2] = cvt_pk_bf16(y.x, y.y);
                ap[3] = cvt_pk_bf16(y.z, y.w);
                afr[mt][kt] = a;
            }
        }
        int   sidx[2][4];
        float nrm[2][4];
        #pragma unroll
        for (int mt = 0; mt < 2; ++mt) {
            #pragma unroll
            for (int r = 0; r < 4; ++r) {
                const int pos = c0 + mt * 16 + quad * 4 + r;
                const int pe  = perm[off0 + min(pos, deg - 1)];
                sidx[mt][r] = src[pe];
                nrm[mt][r]  = (pos < deg) ? norm[pe] : 0.0f;
            }
        }
        #pragma unroll
        for (int g = 0; g < 4; ++g) {
            float hv[2][2][4];
            #pragma unroll
            for (int t2 = 0; t2 < 2; ++t2)
                #pragma unroll
                for (int mt = 0; mt < 2; ++mt)
                    #pragma unroll
                    for (int r = 0; r < 4; ++r)
                        hv[t2][mt][r] =
                            h[sidx[mt][r] * D + (g * 2 + t2) * 16 + row16];
            f32x4 acc[2][2];
            #pragma unroll
            for (int t2 = 0; t2 < 2; ++t2) {
                const int nt = g * 2 + t2;
                short8 bfr[4];
                #pragma unroll
                for (int kt = 0; kt < 4; ++kt)
                    bfr[kt] = fragE[(nt * 4 + kt) * 64 + lane];
                f32x4 a0 = {0.f, 0.f, 0.f, 0.f};
                f32x4 a1 = {0.f, 0.f, 0.f, 0.f};
                #pragma unroll
                for (int kt = 0; kt < 4; ++kt) {
                    a0 = __builtin_amdgcn_mfma_f32_16x16x32_bf16(afr[0][kt], bfr[kt], a0, 0, 0, 0);
                    a1 = __builtin_amdgcn_mfma_f32_16x16x32_bf16(afr[1][kt], bfr[kt], a1, 0, 0, 0);
                }
                acc[t2][0] = a0;
                acc[t2][1] = a1;
            }
            #pragma unroll
            for (int t2 = 0; t2 < 2; ++t2) {
                const int nt = g * 2 + t2;
                const float bev = be[nt * 16 + row16];
                float s = 0.0f;
                #pragma unroll
                for (int r = 0; r < 4; ++r) {
                    s += nrm[0][r] * fmaxf(hv[t2][0][r] + acc[t2][0][r] + bev, 0.0f);
                    s += nrm[1][r] * fmaxf(hv[t2][1][r] + acc[t2][1][r] + bev, 0.0f);
                }
                colsum[nt] += s;
            }
        }
    }
    #pragma unroll
    for (int nt = 0; nt < 8; ++nt) {
        float v = colsum[nt];
        v += __shfl_xor(v, 16, 64);
        v += __shfl_xor(v, 32, 64);
        colsum[nt] = v;
    }
    const int base = node * D;
    #pragma unroll
    for (int j = 0; j < 2; ++j) {
        const int nt  = quad * 2 + j;
        const int col = nt * 16 + row16;
        out[base + col] += colsum[nt];
    }
}

extern "C" void kernel_launch(void* const* d_in, const int* in_sizes, int n_in,
                              void* d_out, int out_size, void* d_ws, size_t ws_size,
                              hipStream_t stream) {
    const float* node_feats = (const float*)d_in[0];
    const float* edge_feats = (const float*)d_in[1];
    const float* degs       = (const float*)d_in[2];
    const float* norm       = (const float*)d_in[3];
    const int*   src        = (const int*)d_in[4];
    const int*   dst        = (const int*)d_in[5];
    const float* Wn         = (const float*)d_in[6];
    const float* bn         = (const float*)d_in[7];
    const float* We         = (const float*)d_in[8];
    const float* be         = (const float*)d_in[9];
    const float* res_w      = (const float*)d_in[10];

    float* out = (float*)d_out;

    // Workspace layout (bytes), primary path:
    //   h:     [0,        10240000)   N*D fp32
    //   snp:   [10240000, 15360000)   E int2 {src, norm_bits} in sorted order
    //   count: [15360000, 15440000)   N i32 (scan in place; scatter cursor)
    //   off:   [15440000, 15520004)   (N+1) i32 durable run offsets
    //   fragE: [15600000, +32768)     We bf16 fragments
    //   fragH: [15700000, +32768)     Wn hi fragments
    //   fragL: [15800000, +32768)     Wn lo fragments
    //   efs:   [16000000, 179840000)  E x 256B bf16 rows, dst-sorted
    char* ws = (char*)d_ws;
    float*  h_ws  = (float*)(ws);
    int2*   snp   = (int2*)(ws + 10240000);
    int*    count = (int*)(ws + 15360000);
    int*    off   = (int*)(ws + 15440000);
    short8* fragE = (short8*)(ws + 15600000);
    short8* fragH = (short8*)(ws + 15700000);
    short8* fragL = (short8*)(ws + 15800000);
    short8* efs   = (short8*)(ws + 16000000);

    const bool big_ws = (ws_size >= (size_t)179840000);

    // 0) weight fragments + histogram zero
    prep_kernel<<<8, 256, 0, stream>>>(We, Wn, fragE, fragH, fragL, count);

    // 1) histogram + scan (scan keeps durable off[] copy)
    hist_kernel<<<SCAT_BLOCKS, 256, 0, stream>>>(dst, count);
    scan_kernel<<<1, 1024, 0, stream>>>(count, count, off);

    if (big_ws) {
        // 2) node path + streaming scatter-convert of ef -> efs (bf16, sorted)
        mid_kernel<<<N_TILES_NODE + CONV_BLOCKS, 256, 0, stream>>>(
            dst, count, src, norm, edge_feats, efs, snp,
            node_feats, degs, fragH, fragL, bn, res_w, h_ws, out);

        // 3) edge path: fully streaming reads, register aggregation
        edge_kernel<<<EDGE_BLOCKS, 256, 0, stream>>>(efs, snp, off, fragE, be,
                                                     h_ws, out);
    } else {
        // Fallback (R6 structure): perm at snp slot (E i32 fits in 5.12 MB)
        int* perm = (int*)(ws + 10240000);
        mid_fb<<<N_TILES_NODE + SCAT_BLOCKS, 256, 0, stream>>>(
            dst, count, perm, node_feats, degs, fragH, fragL,
            bn, res_w, h_ws, out);
        edge_fb<<<EDGE_BLOCKS, 256, 0, stream>>>(edge_feats, norm, src, perm,
                                                 off, fragE, be, h_ws, out);
    }
}

// Round 9
// 623.561 us; speedup vs baseline: 1.3652x; 1.3652x over previous
//
#include <hip/hip_runtime.h>
#include <hip/hip_bf16.h>

// Problem constants (fixed by the reference file).
constexpr int N_NODES = 20000;
constexpr int N_EDGES = 640000;
constexpr int D = 128;          // D_IN == D_OUT == 128
constexpr int N_TILES_NODE = (N_NODES + 63) / 64;   // 313
constexpr int N_TILES_EDGE = N_EDGES / 128;         // 5000
constexpr int SCAT_BLOCKS  = (N_EDGES + 255) / 256; // 2500
constexpr int N_CHUNKS     = (N_NODES + 255) / 256; // 79 scan chunks
constexpr int TILE_LD = 33;     // 32 m + 1 pad: conflict-free both ways

typedef float  f32x4  __attribute__((ext_vector_type(4)));
typedef short  short8 __attribute__((ext_vector_type(8)));

// fp32 -> bf16 bits, round-to-nearest-even (scalar)
__device__ inline short f2bf(float f) {
    unsigned u = __builtin_bit_cast(unsigned, f);
    u += 0x7fffu + ((u >> 16) & 1u);
    return (short)(u >> 16);
}
__device__ inline float bf2f(short s) {
    unsigned u = ((unsigned)(unsigned short)s) << 16;
    return __builtin_bit_cast(float, u);
}
// packed fp32x2 -> bf16x2 (RNE), single HW instruction
__device__ inline unsigned cvt_pk_bf16(float a, float b) {
    unsigned r;
    asm("v_cvt_pk_bf16_f32 %0, %1, %2" : "=v"(r) : "v"(a), "v"(b));
    return r;
}
// 64-lane inclusive scan via shfl_up
__device__ __forceinline__ int scan64(int v, int lane) {
    #pragma unroll
    for (int off = 1; off < 64; off <<= 1) {
        const int nbr = __shfl_up(v, off, 64);
        if (lane >= off) v += nbr;
    }
    return v;
}

// ---------------------------------------------------------------------------
// Prep: weight fragments (We -> fragE bf16; Wn -> fragH/fragL hi/lo split)
// + zero the counting-sort histogram.
// ---------------------------------------------------------------------------
__global__ __launch_bounds__(256) void prep_kernel(
    const float* __restrict__ We, const float* __restrict__ Wn,
    short8* __restrict__ fragE, short8* __restrict__ fragH,
    short8* __restrict__ fragL, int* __restrict__ count)
{
    const int t = blockIdx.x * 256 + threadIdx.x;   // 2048 threads
    for (int i = t; i < N_NODES; i += 2048) count[i] = 0;

    const int n = t >> 4, k8 = t & 15;
    const int kt = k8 >> 2, q = k8 & 3;
    const int fi = ((n >> 4) * 4 + kt) * 64 + q * 16 + (n & 15);

    {
        const float4 x = *(const float4*)(We + n * D + k8 * 8);
        const float4 y = *(const float4*)(We + n * D + k8 * 8 + 4);
        short8 s;
        unsigned* sp = (unsigned*)&s;
        sp[0] = cvt_pk_bf16(x.x, x.y);
        sp[1] = cvt_pk_bf16(x.z, x.w);
        sp[2] = cvt_pk_bf16(y.x, y.y);
        sp[3] = cvt_pk_bf16(y.z, y.w);
        fragE[fi] = s;
    }
    {
        const float4 x = *(const float4*)(Wn + n * D + k8 * 8);
        const float4 y = *(const float4*)(Wn + n * D + k8 * 8 + 4);
        const float v[8] = {x.x, x.y, x.z, x.w, y.x, y.y, y.z, y.w};
        short8 hi, lo;
        #pragma unroll
        for (int j = 0; j < 8; ++j) {
            hi[j] = f2bf(v[j]);
            lo[j] = f2bf(v[j] - bf2f(hi[j]));
        }
        fragH[fi] = hi;
        fragL[fi] = lo;
    }
}

// ---------------------------------------------------------------------------
// Counting sort: histogram + PARALLEL 3-dispatch scan (the single-block scan
// was ~80-120 us of pure serialization on 1 of 256 CUs).
// ---------------------------------------------------------------------------
__global__ __launch_bounds__(256) void hist_kernel(
    const int* __restrict__ dst, int* __restrict__ count)
{
    const int e = blockIdx.x * 256 + threadIdx.x;
    if (e < N_EDGES) atomicAdd(&count[dst[e]], 1);
}

// Per-chunk local exclusive scans, in place; chunk totals -> bsum.
__global__ __launch_bounds__(256) void scan_local(
    int* __restrict__ count, int* __restrict__ bsum)
{
    __shared__ int wsum[4];
    const int tid = threadIdx.x;
    const int lane = tid & 63, w = tid >> 6;
    const int idx = blockIdx.x * 256 + tid;
    const int v = (idx < N_NODES) ? count[idx] : 0;
    const int incl = scan64(v, lane);
    if (lane == 63) wsum[w] = incl;
    __syncthreads();
    int woff = 0;
    #pragma unroll
    for (int j = 0; j < 4; ++j) if (j < w) woff += wsum[j];
    if (idx < N_NODES) count[idx] = woff + incl - v;
    if (tid == 255) bsum[blockIdx.x] = woff + incl;   // chunk total
}

// Exclusive scan of the 79 chunk totals (single wave).
__global__ __launch_bounds__(64) void scan_top(int* __restrict__ bsum)
{
    const int tid = threadIdx.x;
    const int b0 = (tid < N_CHUNKS) ? bsum[tid] : 0;
    const int i0 = scan64(b0, tid);
    const int t0 = __shfl(i0, 63, 64);
    const int b1 = (64 + tid < N_CHUNKS) ? bsum[64 + tid] : 0;
    const int i1 = scan64(b1, tid);
    if (tid < N_CHUNKS) bsum[tid] = i0 - b0;
    if (64 + tid < N_CHUNKS) bsum[64 + tid] = t0 + i1 - b1;
}

// Add chunk offsets -> final exclusive prefix (scatter cursor), in place.
__global__ __launch_bounds__(256) void scan_add(
    int* __restrict__ count, const int* __restrict__ bsum)
{
    const int idx = blockIdx.x * 256 + threadIdx.x;
    if (idx < N_NODES) count[idx] += bsum[blockIdx.x];
}

// ---------------------------------------------------------------------------
// Node tile body: h = nf @ Wn.T + bn (hi/lo bf16 split, ~fp32 exact),
// h -> workspace; out = relu(h + res_w) / degs (residual init).
// ---------------------------------------------------------------------------
__device__ __forceinline__ void node_tile(
    int tb, int tid,
    const float* __restrict__ nf, const float* __restrict__ degs,
    const short8* __restrict__ fragH, const short8* __restrict__ fragL,
    const float* __restrict__ bn, const float* __restrict__ res_w,
    float* __restrict__ h_ws, float* __restrict__ out)
{
    const int lane = tid & 63, wave = tid >> 6;
    const int quad = lane >> 4, row16 = lane & 15;
    const int mbase = tb * 64 + wave * 16;

    const int arow = min(mbase + row16, N_NODES - 1);
    short8 ah[4], al[4];
    const float* p = nf + arow * D + quad * 8;
    #pragma unroll
    for (int kt = 0; kt < 4; ++kt) {
        const float4 x = *(const float4*)(p + kt * 32);
        const float4 y = *(const float4*)(p + kt * 32 + 4);
        const float v[8] = {x.x, x.y, x.z, x.w, y.x, y.y, y.z, y.w};
        #pragma unroll
        for (int j = 0; j < 8; ++j) {
            ah[kt][j] = f2bf(v[j]);
            al[kt][j] = f2bf(v[j] - bf2f(ah[kt][j]));
        }
    }

    int   orow[4];
    float dinv[4];
    #pragma unroll
    for (int r = 0; r < 4; ++r) {
        orow[r] = mbase + quad * 4 + r;
        dinv[r] = 1.0f / degs[min(orow[r], N_NODES - 1)];
    }

    #pragma unroll
    for (int nt = 0; nt < 8; ++nt) {
        f32x4 acc = {0.f, 0.f, 0.f, 0.f};
        #pragma unroll
        for (int kt = 0; kt < 4; ++kt) {
            const short8 bh = fragH[(nt * 4 + kt) * 64 + lane];
            const short8 bl = fragL[(nt * 4 + kt) * 64 + lane];
            acc = __builtin_amdgcn_mfma_f32_16x16x32_bf16(al[kt], bh, acc, 0, 0, 0);
            acc = __builtin_amdgcn_mfma_f32_16x16x32_bf16(ah[kt], bl, acc, 0, 0, 0);
            acc = __builtin_amdgcn_mfma_f32_16x16x32_bf16(ah[kt], bh, acc, 0, 0, 0);
        }
        const int col = nt * 16 + row16;
        const float bnv = bn[col], rwv = res_w[col];
        #pragma unroll
        for (int r = 0; r < 4; ++r) {
            if (orow[r] < N_NODES) {
                const float hv = acc[r] + bnv;
                h_ws[orow[r] * D + col] = hv;
                out[orow[r] * D + col] = fmaxf(hv + rwv, 0.0f) * dinv[r];
            }
        }
    }
}

// ---------------------------------------------------------------------------
// Mid kernel: node tiles (blocks [0, N_TILES_NODE)) + scatter (rest).
// Scatter writes ONE 8B int2 (perm,dst) per edge.
// ---------------------------------------------------------------------------
__global__ __launch_bounds__(256) void mid_kernel(
    const int* __restrict__ dst, int* __restrict__ cursor,
    int2* __restrict__ pd,
    const float* __restrict__ nf, const float* __restrict__ degs,
    const short8* __restrict__ fragH, const short8* __restrict__ fragL,
    const float* __restrict__ bn, const float* __restrict__ res_w,
    float* __restrict__ h_ws, float* __restrict__ out)
{
    if (blockIdx.x < N_TILES_NODE) {
        node_tile(blockIdx.x, threadIdx.x, nf, degs, fragH, fragL,
                  bn, res_w, h_ws, out);
    } else {
        const int e = (blockIdx.x - N_TILES_NODE) * 256 + threadIdx.x;
        if (e < N_EDGES) {
            const int d = dst[e];
            const int pos = atomicAdd(&cursor[d], 1);
            pd[pos] = make_int2(e, d);
        }
    }
}

// ---------------------------------------------------------------------------
// Edge kernel (measured-best R4 structure, restored verbatim):
//   e   = ef[perm] @ We.T + be   (bf16 MFMA, B-fragments from global fragE)
//   msg = norm * relu(h[src] + e)
//   per-wave LDS segmented sum over sorted-dst runs; one atomic/run/col.
// Wave-private tile/sdst (in-order DS pipe), no __syncthreads.
// ---------------------------------------------------------------------------
__global__ __launch_bounds__(256) void edge_kernel(
    const float* __restrict__ ef, const float* __restrict__ norm,
    const int* __restrict__ src, const int2* __restrict__ pd,
    const short8* __restrict__ fragE, const float* __restrict__ be,
    const float* __restrict__ h, float* __restrict__ out)
{
    __shared__ float tile[4][32 * TILE_LD]; // 16896 B: per-wave [c][m]
    __shared__ int   sdst[4][32];           // 512 B

    const int t = threadIdx.x;
    const int lane  = t & 63;
    const int quad  = lane >> 4;
    const int row16 = lane & 15;
    const int wave  = t >> 6;
    const int p0 = blockIdx.x * 128 + wave * 32;   // 32 sorted positions/wave

    int2 pdv = make_int2(0, 0);
    if (lane < 32) {
        pdv = pd[p0 + lane];
        sdst[wave][lane] = pdv.y;
    }

    // ---- A fragments: perm via cross-lane shfl, gather edge rows, fp32->bf16
    short8 afr[2][4];
    #pragma unroll
    for (int mt = 0; mt < 2; ++mt) {
        const int erow = __shfl(pdv.x, mt * 16 + row16, 64);
        const float* p = ef + erow * D + quad * 8;
        #pragma unroll
        for (int kt = 0; kt < 4; ++kt) {
            const float4 x = *(const float4*)(p + kt * 32);
            const float4 y = *(const float4*)(p + kt * 32 + 4);
            short8 a;
            unsigned* ap = (unsigned*)&a;
            ap[0] = cvt_pk_bf16(x.x, x.y);
            ap[1] = cvt_pk_bf16(x.z, x.w);
            ap[2] = cvt_pk_bf16(y.x, y.y);
            ap[3] = cvt_pk_bf16(y.z, y.w);
            afr[mt][kt] = a;
        }
    }

    // ---- Edge metadata for the epilogue rows this lane owns
    int   sidx[2][4];
    float nrm[2][4];
    #pragma unroll
    for (int mt = 0; mt < 2; ++mt) {
        #pragma unroll
        for (int r = 0; r < 4; ++r) {
            const int pe = __shfl(pdv.x, mt * 16 + quad * 4 + r, 64);
            sidx[mt][r] = src[pe];
            nrm[mt][r]  = norm[pe];
        }
    }

    float* tw = &tile[wave][0];
    const int* sw = &sdst[wave][0];

    #pragma unroll
    for (int g = 0; g < 4; ++g) {
        // (1) h prefetch for this group's two 16-col tiles
        float hv[2][2][4];
        #pragma unroll
        for (int t2 = 0; t2 < 2; ++t2)
            #pragma unroll
            for (int mt = 0; mt < 2; ++mt)
                #pragma unroll
                for (int r = 0; r < 4; ++r)
                    hv[t2][mt][r] = h[sidx[mt][r] * D + (g * 2 + t2) * 16 + row16];

        // (2) MFMA both column tiles
        f32x4 acc[2][2];
        #pragma unroll
        for (int t2 = 0; t2 < 2; ++t2) {
            const int nt = g * 2 + t2;
            short8 bfr[4];
            #pragma unroll
            for (int kt = 0; kt < 4; ++kt)
                bfr[kt] = fragE[(nt * 4 + kt) * 64 + lane];
            f32x4 a0 = {0.f, 0.f, 0.f, 0.f};
            f32x4 a1 = {0.f, 0.f, 0.f, 0.f};
            #pragma unroll
            for (int kt = 0; kt < 4; ++kt) {
                a0 = __builtin_amdgcn_mfma_f32_16x16x32_bf16(afr[0][kt], bfr[kt], a0, 0, 0, 0);
                a1 = __builtin_amdgcn_mfma_f32_16x16x32_bf16(afr[1][kt], bfr[kt], a1, 0, 0, 0);
            }
            acc[t2][0] = a0;
            acc[t2][1] = a1;
        }

        // (3) epilogue: msg = norm * relu(h + e + be) -> LDS tile [c][m]
        #pragma unroll
        for (int t2 = 0; t2 < 2; ++t2) {
            const int col = (g * 2 + t2) * 16 + row16;
            const float bev = be[col];
            float* tp = tw + (t2 * 16 + row16) * TILE_LD;
            #pragma unroll
            for (int r = 0; r < 4; ++r) {
                const int m0 = quad * 4 + r;
                tp[m0]      = nrm[0][r] * fmaxf(hv[t2][0][r] + acc[t2][0][r] + bev, 0.0f);
                tp[m0 + 16] = nrm[1][r] * fmaxf(hv[t2][1][r] + acc[t2][1][r] + bev, 0.0f);
            }
        }

        // (4) segmented scan: lane = c*2 + chunk; chunk covers 16 sorted rows.
        {
            const int c = lane >> 1;
            const int mbeg = (lane & 1) * 16;
            const float* sp = tw + c * TILE_LD;
            const int gcol = g * 32 + c;
            int cur = sw[mbeg];
            float sum = 0.0f;
            #pragma unroll
            for (int m = mbeg; m < mbeg + 16; ++m) {
                const int dm = sw[m];
                const float v = sp[m];
                if (dm != cur) {
                    atomicAdd(&out[cur * D + gcol], sum);
                    sum = 0.0f;
                    cur = dm;
                }
                sum += v;
            }
            atomicAdd(&out[cur * D + gcol], sum);
        }
    }
}

extern "C" void kernel_launch(void* const* d_in, const int* in_sizes, int n_in,
                              void* d_out, int out_size, void* d_ws, size_t ws_size,
                              hipStream_t stream) {
    const float* node_feats = (const float*)d_in[0];
    const float* edge_feats = (const float*)d_in[1];
    const float* degs       = (const float*)d_in[2];
    const float* norm       = (const float*)d_in[3];
    const int*   src        = (const int*)d_in[4];
    const int*   dst        = (const int*)d_in[5];
    const float* Wn         = (const float*)d_in[6];
    const float* bn         = (const float*)d_in[7];
    const float* We         = (const float*)d_in[8];
    const float* be         = (const float*)d_in[9];
    const float* res_w      = (const float*)d_in[10];

    float* out = (float*)d_out;

    // Workspace layout (bytes):
    //   h:      [0,        10240000)   N*D fp32
    //   pd:     [10240000, 15360000)   E int2 (perm, dst) packed
    //   count:  [15360000, 15440000)   N i32 (scan in place; scatter cursor)
    //   bsum:   [15440000, +320)       scan chunk totals
    //   fragE:  [15500000, +32768)     We bf16 fragments
    //   fragH:  [15600000, +32768)     Wn hi fragments
    //   fragL:  [15700000, +32768)     Wn lo fragments
    char* ws = (char*)d_ws;
    float*  h_ws  = (float*)(ws);
    int2*   pd    = (int2*)(ws + 10240000);
    int*    count = (int*)(ws + 15360000);
    int*    bsum  = (int*)(ws + 15440000);
    short8* fragE = (short8*)(ws + 15500000);
    short8* fragH = (short8*)(ws + 15600000);
    short8* fragL = (short8*)(ws + 15700000);

    // 0) weight fragments + histogram zero
    prep_kernel<<<8, 256, 0, stream>>>(We, Wn, fragE, fragH, fragL, count);

    // 1) histogram + parallel scan (3 tiny dispatches, all CUs)
    hist_kernel<<<SCAT_BLOCKS, 256, 0, stream>>>(dst, count);
    scan_local<<<N_CHUNKS, 256, 0, stream>>>(count, bsum);
    scan_top<<<1, 64, 0, stream>>>(bsum);
    scan_add<<<N_CHUNKS, 256, 0, stream>>>(count, bsum);

    // 2) node path + scatter, merged (independent work, one dispatch)
    mid_kernel<<<N_TILES_NODE + SCAT_BLOCKS, 256, 0, stream>>>(
        dst, count, pd, node_feats, degs, fragH, fragL, bn, res_w, h_ws, out);

    // 3) edge path: sorted-order GEMM + per-wave segmented aggregation
    edge_kernel<<<N_TILES_EDGE, 256, 0, stream>>>(edge_feats, norm, src, pd,
                                                  fragE, be, h_ws, out);
}